// Round 10
// baseline (666.953 us; speedup 1.0000x reference)
//
#include <hip/hip_runtime.h>

#define BATCH 2048
#define NTRI 165
#define NPAIR 45
#define NSTEP 14
#define UCHUNKS (NSTEP * 3 * 64)   // 2688 16B chunks = 43008 B
#define ROWS_PER_BLOCK 4
#define NBLK (BATCH / ROWS_PER_BLOCK)   // 512
#define ABL_REP 8                  // additive-ablation repeats of the MFMA loop

typedef __attribute__((ext_vector_type(8))) short s16x8;
typedef __attribute__((ext_vector_type(16))) float f32x16;
typedef __attribute__((ext_vector_type(4))) int i32x4;

// ---- compile-time tables ----
struct TriTab { unsigned char a[NTRI], b[NTRI], c[NTRI]; };
constexpr TriTab make_tri() {
  TriTab t{}; int q = 0;
  for (int a = 0; a < 9; a++) for (int b = a; b < 9; b++) for (int c = b; c < 9; c++) {
    t.a[q] = (unsigned char)a; t.b[q] = (unsigned char)b; t.c[q] = (unsigned char)c; q++;
  }
  return t;
}
constexpr TriTab TRI = make_tri();

struct PairTab { unsigned char a[NPAIR], b[NPAIR]; };
constexpr PairTab make_pair() {
  PairTab t{}; int q = 0;
  for (int a = 0; a < 9; a++) for (int b = a; b < 9; b++) {
    t.a[q] = (unsigned char)a; t.b[q] = (unsigned char)b; q++;
  }
  return t;
}
constexpr PairTab PAIR = make_pair();

// ---- prep: build bf16 U^T table in A-fragment-major order (direct table lookup) ----
__global__ void prep_kernel(const float* __restrict__ U30, const float* __restrict__ U20, const float* __restrict__ U10,
                            const float* __restrict__ U31, const float* __restrict__ U21, const float* __restrict__ U11,
                            const float* __restrict__ U32, const float* __restrict__ U22, const float* __restrict__ U12,
                            unsigned short* __restrict__ wsB) {
  int t = blockIdx.x * blockDim.x + threadIdx.x;
  if (t >= UCHUNKS * 8) return;
  int j = t & 7;
  int lane = (t >> 3) & 63;
  int cf = t >> 9;                 // s*3+ct, 0..41
  int s = cf / 3, ct = cf % 3;
  int n = ct * 32 + (lane & 31);
  int k = s * 16 + (lane >> 5) * 8 + j;
  const float* U3[3] = {U30, U31, U32};
  const float* U2[3] = {U20, U21, U22};
  const float* U1[3] = {U10, U11, U12};
  float val = 0.f;
  if (n < 54) {
    if (k < NTRI) {
      int o = n / 6, j3 = n % 6;
      int ir = (o > 0) + (o > 3); int lo = o - (ir == 1 ? 1 : (ir == 2 ? 4 : 0));
      int a = TRI.a[k], b = TRI.b[k], cc = TRI.c[k];
      int pm[6][3] = {{a,b,cc},{a,cc,b},{b,a,cc},{b,cc,a},{cc,a,b},{cc,b,a}};
      for (int p = 0; p < 6; p++) {
        bool dup = false;
        for (int rr = 0; rr < p; rr++)
          if (pm[rr][0] == pm[p][0] && pm[rr][1] == pm[p][1] && pm[rr][2] == pm[p][2]) dup = true;
        if (!dup) val += U3[ir][(((lo * 9 + pm[p][0]) * 9 + pm[p][1]) * 9 + pm[p][2]) * 6 + j3];
      }
    }
  } else if (n < 81) {
    if (k >= NTRI && k < NTRI + NPAIR) {
      int o = (n - 54) / 3, j2 = (n - 54) % 3;
      int ir = (o > 0) + (o > 3); int lo = o - (ir == 1 ? 1 : (ir == 2 ? 4 : 0));
      int p = k - NTRI;
      int a = PAIR.a[p], b = PAIR.b[p];
      val = U2[ir][((lo * 9 + a) * 9 + b) * 3 + j2];
      if (a != b) val += U2[ir][((lo * 9 + b) * 9 + a) * 3 + j2];
    }
  } else if (n < 90) {
    if (k >= 210 && k < 219) {
      int o = n - 81;
      int ir = (o > 0) + (o > 3); int lo = o - (ir == 1 ? 1 : (ir == 2 ? 4 : 0));
      val = U1[ir][lo * 9 + (k - 210)];
    }
  }
  unsigned u = __float_as_uint(val);
  unsigned r = (u + 0x7FFFu + ((u >> 16) & 1u)) >> 16;   // RNE to bf16
  wsB[t] = (unsigned short)r;
}

// ---- main: R6 structure (91 us baseline) + additive ablation of the MFMA loop ----
__global__ __launch_bounds__(256) void symcon_mfma(
    const float* __restrict__ x, const int* __restrict__ indices,
    const float* __restrict__ w, const unsigned short* __restrict__ wsB,
    float* __restrict__ out)
{
  __shared__ __align__(16) unsigned short Ut[UCHUNKS * 8];   // 43008 B

  const int tid = threadIdx.x;
  {
    const i32x4* src = (const i32x4*)wsB;
    i32x4* dst = (i32x4*)Ut;
    for (int i = tid; i < UCHUNKS; i += 256) dst[i] = src[i];
  }
  __syncthreads();

  const int wave = tid >> 6;
  const int l = tid & 63;
  const int l5 = l & 31;
  const int g2 = l >> 5;
  const int c = wave * 32 + l5;

  const int row0 = blockIdx.x * ROWS_PER_BLOCK;

  float xnx[9];
  {
    const float* xp = x + ((size_t)row0 * 128 + c) * 9;
#pragma unroll
    for (int i = 0; i < 9; i++) xnx[i] = xp[i];
  }

#pragma unroll 1
  for (int sp = 0; sp < ROWS_PER_BLOCK; sp++) {
    const int b = row0 + sp;

    float xx[9];
#pragma unroll
    for (int i = 0; i < 9; i++) xx[i] = xnx[i];

    {
      const int nb = (sp < ROWS_PER_BLOCK - 1) ? (b + 1) : b;
      const float* xp = x + ((size_t)nb * 128 + c) * 9;
#pragma unroll
      for (int i = 0; i < 9; i++) xnx[i] = xp[i];
    }

    // ======== REAL 14-step loop (R6 verbatim) ========
    f32x16 acc[3];
#pragma unroll
    for (int ct = 0; ct < 3; ct++)
#pragma unroll
      for (int i = 0; i < 16; i++) acc[ct][i] = 0.f;

#pragma unroll
    for (int s = 0; s < NSTEP; s++) {
      float m[16];
#pragma unroll
      for (int t = 0; t < 16; t++) {
        const int k = s * 16 + t;
        if (k < NTRI)              m[t] = xx[TRI.a[k]] * xx[TRI.b[k]] * xx[TRI.c[k]];
        else if (k < NTRI + NPAIR) m[t] = xx[PAIR.a[k - NTRI]] * xx[PAIR.b[k - NTRI]];
        else if (k < 219)          m[t] = xx[k - 210];
        else                       m[t] = 0.f;
      }
      unsigned pk[4];
#pragma unroll
      for (int u = 0; u < 4; u++) {
        float lo = g2 ? m[8 + 2 * u]     : m[2 * u];
        float hi = g2 ? m[8 + 2 * u + 1] : m[2 * u + 1];
        asm("v_cvt_pk_bf16_f32 %0, %1, %2" : "=v"(pk[u]) : "v"(lo), "v"(hi));
      }
      i32x4 bi;
      bi[0] = (int)pk[0]; bi[1] = (int)pk[1]; bi[2] = (int)pk[2]; bi[3] = (int)pk[3];
      s16x8 bf = __builtin_bit_cast(s16x8, bi);
#pragma unroll
      for (int ct = 0; ct < 3; ct++) {
        i32x4 ua = ((const i32x4*)Ut)[(s * 3 + ct) * 64 + l];
        s16x8 af = __builtin_bit_cast(s16x8, ua);
        acc[ct] = __builtin_amdgcn_mfma_f32_32x32x16_bf16(af, bf, acc[ct], 0, 0, 0);
      }
    }

    // ======== REAL epilogue (R6 verbatim) ========
    const int e = indices[b];
    const float* wbase = w + (size_t)e * 30 * 128 + c;
    float wv[30];
#pragma unroll
    for (int p = 0; p < 30; p++) wv[p] = wbase[p * 128];

    float* orow = out + (size_t)b * 1152;
#pragma unroll
    for (int o = 0; o < 9; o++) {
      const int ir = (o > 0) + (o > 3);
      float p0 = 0.f, p1 = 0.f;
#pragma unroll
      for (int k3 = 0; k3 < 6; k3++) {
        const int n = 6 * o + k3;
        const int nl = n & 31, ct = n >> 5;
        const int reg = (nl & 3) + 4 * (nl >> 3);
        const float cf = wv[ir * 10 + k3];
        if (((nl >> 2) & 1) == 0) p0 = fmaf(acc[ct][reg], cf, p0);
        else                      p1 = fmaf(acc[ct][reg], cf, p1);
      }
#pragma unroll
      for (int k2 = 0; k2 < 3; k2++) {
        const int n = 54 + 3 * o + k2;
        const int nl = n & 31, ct = n >> 5;
        const int reg = (nl & 3) + 4 * (nl >> 3);
        const float cf = wv[ir * 10 + 6 + k2];
        if (((nl >> 2) & 1) == 0) p0 = fmaf(acc[ct][reg], cf, p0);
        else                      p1 = fmaf(acc[ct][reg], cf, p1);
      }
      {
        const int n = 81 + o;
        const int nl = n & 31, ct = n >> 5;
        const int reg = (nl & 3) + 4 * (nl >> 3);
        const float cf = wv[ir * 10 + 9];
        if (((nl >> 2) & 1) == 0) p0 = fmaf(acc[ct][reg], cf, p0);
        else                      p1 = fmaf(acc[ct][reg], cf, p1);
      }
      float p = g2 ? p1 : p0;
      p += __shfl_xor(p, 32);
      const int col = (o == 0) ? c : (o < 4 ? 128 + 3 * c + (o - 1) : 512 + 5 * c + (o - 4));
      const bool mine = (o < 5) ? (g2 == 0) : (g2 == 1);
      if (mine) orow[col] = p;
    }

    // ======== ADDITIVE ABLATION: 8 serially-chained dummy copies of the loop ========
    // Seeded from the real acc (so dummies start after the real loop), chained
    // through an opaque-zero so repeat r+1 depends on repeat r. Results sunk via
    // asm; output untouched. dur ~= 91 + 8 * (loop share).
    float chain = acc[0][0] + acc[1][0] + acc[2][0];
#pragma unroll 1
    for (int rep = 0; rep < ABL_REP; rep++) {
      unsigned z;
      asm("v_and_b32 %0, 0, %1" : "=v"(z) : "v"(__float_as_uint(chain)));  // opaque 0
      const float zf = __uint_as_float(z);
      float xd[9];
#pragma unroll
      for (int i = 0; i < 9; i++) xd[i] = xx[i] + zf;

      f32x16 ad[3];
#pragma unroll
      for (int ct = 0; ct < 3; ct++)
#pragma unroll
        for (int i = 0; i < 16; i++) ad[ct][i] = 0.f;

#pragma unroll
      for (int s = 0; s < NSTEP; s++) {
        float m[16];
#pragma unroll
        for (int t = 0; t < 16; t++) {
          const int k = s * 16 + t;
          if (k < NTRI)              m[t] = xd[TRI.a[k]] * xd[TRI.b[k]] * xd[TRI.c[k]];
          else if (k < NTRI + NPAIR) m[t] = xd[PAIR.a[k - NTRI]] * xd[PAIR.b[k - NTRI]];
          else if (k < 219)          m[t] = xd[k - 210];
          else                       m[t] = 0.f;
        }
        unsigned pk[4];
#pragma unroll
        for (int u = 0; u < 4; u++) {
          float lo = g2 ? m[8 + 2 * u]     : m[2 * u];
          float hi = g2 ? m[8 + 2 * u + 1] : m[2 * u + 1];
          asm("v_cvt_pk_bf16_f32 %0, %1, %2" : "=v"(pk[u]) : "v"(lo), "v"(hi));
        }
        i32x4 bi;
        bi[0] = (int)pk[0]; bi[1] = (int)pk[1]; bi[2] = (int)pk[2]; bi[3] = (int)pk[3];
        s16x8 bf = __builtin_bit_cast(s16x8, bi);
#pragma unroll
        for (int ct = 0; ct < 3; ct++) {
          i32x4 ua = ((const i32x4*)Ut)[(s * 3 + ct) * 64 + l];
          s16x8 af = __builtin_bit_cast(s16x8, ua);
          ad[ct] = __builtin_amdgcn_mfma_f32_32x32x16_bf16(af, bf, ad[ct], 0, 0, 0);
        }
      }
      chain = ad[0][0] + ad[1][0] + ad[2][0];   // keeps all 3 MFMA chains live
    }
    asm volatile("" :: "v"(chain));
  }
}

extern "C" void kernel_launch(void* const* d_in, const int* in_sizes, int n_in,
                              void* d_out, int out_size, void* d_ws, size_t ws_size,
                              hipStream_t stream) {
  const float* x   = (const float*)d_in[0];
  const int*   idx = (const int*)d_in[1];
  const float* w   = (const float*)d_in[2];
  const float* U30 = (const float*)d_in[3];
  const float* U20 = (const float*)d_in[4];
  const float* U10 = (const float*)d_in[5];
  const float* U31 = (const float*)d_in[6];
  const float* U21 = (const float*)d_in[7];
  const float* U11 = (const float*)d_in[8];
  const float* U32 = (const float*)d_in[9];
  const float* U22 = (const float*)d_in[10];
  const float* U12 = (const float*)d_in[11];
  unsigned short* wsB = (unsigned short*)d_ws;
  float* out = (float*)d_out;

  prep_kernel<<<(UCHUNKS * 8 + 255) / 256, 256, 0, stream>>>(U30, U20, U10, U31, U21, U11, U32, U22, U12, wsB);
  symcon_mfma<<<NBLK, 256, 0, stream>>>(x, idx, w, wsB, out);
}

// Round 11
// 104.256 us; speedup vs baseline: 6.3973x; 6.3973x over previous
//
#include <hip/hip_runtime.h>

#define BATCH 2048
#define NTRI 165
#define NPAIR 45
#define NSTEP 14
#define UCHUNKS (NSTEP * 3 * 64)   // 2688 16B chunks = 43008 B
#define ROWS_PER_BLOCK 4
#define NBLK (BATCH / ROWS_PER_BLOCK)   // 512

typedef __attribute__((ext_vector_type(8))) short s16x8;
typedef __attribute__((ext_vector_type(16))) float f32x16;
typedef __attribute__((ext_vector_type(4))) int i32x4;

// ---- compile-time tables ----
struct TriTab { unsigned char a[NTRI], b[NTRI], c[NTRI]; };
constexpr TriTab make_tri() {
  TriTab t{}; int q = 0;
  for (int a = 0; a < 9; a++) for (int b = a; b < 9; b++) for (int c = b; c < 9; c++) {
    t.a[q] = (unsigned char)a; t.b[q] = (unsigned char)b; t.c[q] = (unsigned char)c; q++;
  }
  return t;
}
constexpr TriTab TRI = make_tri();

struct PairTab { unsigned char a[NPAIR], b[NPAIR]; };
constexpr PairTab make_pair() {
  PairTab t{}; int q = 0;
  for (int a = 0; a < 9; a++) for (int b = a; b < 9; b++) {
    t.a[q] = (unsigned char)a; t.b[q] = (unsigned char)b; q++;
  }
  return t;
}
constexpr PairTab PAIR = make_pair();

// ---- prep: build bf16 U^T table in A-fragment-major order (direct table lookup) ----
__global__ void prep_kernel(const float* __restrict__ U30, const float* __restrict__ U20, const float* __restrict__ U10,
                            const float* __restrict__ U31, const float* __restrict__ U21, const float* __restrict__ U11,
                            const float* __restrict__ U32, const float* __restrict__ U22, const float* __restrict__ U12,
                            unsigned short* __restrict__ wsB) {
  int t = blockIdx.x * blockDim.x + threadIdx.x;
  if (t >= UCHUNKS * 8) return;
  int j = t & 7;
  int lane = (t >> 3) & 63;
  int cf = t >> 9;                 // s*3+ct, 0..41
  int s = cf / 3, ct = cf % 3;
  int n = ct * 32 + (lane & 31);
  int k = s * 16 + (lane >> 5) * 8 + j;
  const float* U3[3] = {U30, U31, U32};
  const float* U2[3] = {U20, U21, U22};
  const float* U1[3] = {U10, U11, U12};
  float val = 0.f;
  if (n < 54) {
    if (k < NTRI) {
      int o = n / 6, j3 = n % 6;
      int ir = (o > 0) + (o > 3); int lo = o - (ir == 1 ? 1 : (ir == 2 ? 4 : 0));
      int a = TRI.a[k], b = TRI.b[k], cc = TRI.c[k];
      int pm[6][3] = {{a,b,cc},{a,cc,b},{b,a,cc},{b,cc,a},{cc,a,b},{cc,b,a}};
      for (int p = 0; p < 6; p++) {
        bool dup = false;
        for (int rr = 0; rr < p; rr++)
          if (pm[rr][0] == pm[p][0] && pm[rr][1] == pm[p][1] && pm[rr][2] == pm[p][2]) dup = true;
        if (!dup) val += U3[ir][(((lo * 9 + pm[p][0]) * 9 + pm[p][1]) * 9 + pm[p][2]) * 6 + j3];
      }
    }
  } else if (n < 81) {
    if (k >= NTRI && k < NTRI + NPAIR) {
      int o = (n - 54) / 3, j2 = (n - 54) % 3;
      int ir = (o > 0) + (o > 3); int lo = o - (ir == 1 ? 1 : (ir == 2 ? 4 : 0));
      int p = k - NTRI;
      int a = PAIR.a[p], b = PAIR.b[p];
      val = U2[ir][((lo * 9 + a) * 9 + b) * 3 + j2];
      if (a != b) val += U2[ir][((lo * 9 + b) * 9 + a) * 3 + j2];
    }
  } else if (n < 90) {
    if (k >= 210 && k < 219) {
      int o = n - 81;
      int ir = (o > 0) + (o > 3); int lo = o - (ir == 1 ? 1 : (ir == 2 ? 4 : 0));
      val = U1[ir][lo * 9 + (k - 210)];
    }
  }
  unsigned u = __float_as_uint(val);
  unsigned r = (u + 0x7FFFu + ((u >> 16) & 1u)) >> 16;   // RNE to bf16
  wsB[t] = (unsigned short)r;
}

// ---- main: R6 structure + parity-split accumulators (chain depth 14 -> 7) ----
// R8 measured time ~ chain depth (42-deep = 2.7x of 14-deep); the in-place
// MFMA accumulate RAW chain is the one serial coupling the compiler can't break.
__global__ __launch_bounds__(256) void symcon_mfma(
    const float* __restrict__ x, const int* __restrict__ indices,
    const float* __restrict__ w, const unsigned short* __restrict__ wsB,
    float* __restrict__ out)
{
  __shared__ __align__(16) unsigned short Ut[UCHUNKS * 8];   // 43008 B

  const int tid = threadIdx.x;
  {
    const i32x4* src = (const i32x4*)wsB;
    i32x4* dst = (i32x4*)Ut;
    for (int i = tid; i < UCHUNKS; i += 256) dst[i] = src[i];
  }
  __syncthreads();

  const int wave = tid >> 6;
  const int l = tid & 63;
  const int l5 = l & 31;
  const int g2 = l >> 5;
  const int c = wave * 32 + l5;

  const int row0 = blockIdx.x * ROWS_PER_BLOCK;

  float xnx[9];
  {
    const float* xp = x + ((size_t)row0 * 128 + c) * 9;
#pragma unroll
    for (int i = 0; i < 9; i++) xnx[i] = xp[i];
  }

#pragma unroll 1
  for (int sp = 0; sp < ROWS_PER_BLOCK; sp++) {
    const int b = row0 + sp;

    float xx[9];
#pragma unroll
    for (int i = 0; i < 9; i++) xx[i] = xnx[i];

    {
      const int nb = (sp < ROWS_PER_BLOCK - 1) ? (b + 1) : b;
      const float* xp = x + ((size_t)nb * 128 + c) * 9;
#pragma unroll
      for (int i = 0; i < 9; i++) xnx[i] = xp[i];
    }

    // parity-split accumulators: even s -> accE, odd s -> accO (6 chains, depth 7)
    f32x16 accE[3], accO[3];
#pragma unroll
    for (int ct = 0; ct < 3; ct++)
#pragma unroll
      for (int i = 0; i < 16; i++) { accE[ct][i] = 0.f; accO[ct][i] = 0.f; }

#pragma unroll
    for (int s = 0; s < NSTEP; s++) {
      float m[16];
#pragma unroll
      for (int t = 0; t < 16; t++) {
        const int k = s * 16 + t;
        if (k < NTRI)              m[t] = xx[TRI.a[k]] * xx[TRI.b[k]] * xx[TRI.c[k]];
        else if (k < NTRI + NPAIR) m[t] = xx[PAIR.a[k - NTRI]] * xx[PAIR.b[k - NTRI]];
        else if (k < 219)          m[t] = xx[k - 210];
        else                       m[t] = 0.f;
      }
      unsigned pk[4];
#pragma unroll
      for (int u = 0; u < 4; u++) {
        float lo = g2 ? m[8 + 2 * u]     : m[2 * u];
        float hi = g2 ? m[8 + 2 * u + 1] : m[2 * u + 1];
        asm("v_cvt_pk_bf16_f32 %0, %1, %2" : "=v"(pk[u]) : "v"(lo), "v"(hi));
      }
      i32x4 bi;
      bi[0] = (int)pk[0]; bi[1] = (int)pk[1]; bi[2] = (int)pk[2]; bi[3] = (int)pk[3];
      s16x8 bf = __builtin_bit_cast(s16x8, bi);
#pragma unroll
      for (int ct = 0; ct < 3; ct++) {
        i32x4 ua = ((const i32x4*)Ut)[(s * 3 + ct) * 64 + l];
        s16x8 af = __builtin_bit_cast(s16x8, ua);
        if ((s & 1) == 0) accE[ct] = __builtin_amdgcn_mfma_f32_32x32x16_bf16(af, bf, accE[ct], 0, 0, 0);
        else              accO[ct] = __builtin_amdgcn_mfma_f32_32x32x16_bf16(af, bf, accO[ct], 0, 0, 0);
      }
    }

    // merge parity halves
    f32x16 acc[3];
#pragma unroll
    for (int ct = 0; ct < 3; ct++)
#pragma unroll
      for (int i = 0; i < 16; i++) acc[ct][i] = accE[ct][i] + accO[ct][i];

    // ---- in-register epilogue (R5-validated mapping) ----
    const int e = indices[b];
    const float* wbase = w + (size_t)e * 30 * 128 + c;
    float wv[30];
#pragma unroll
    for (int p = 0; p < 30; p++) wv[p] = wbase[p * 128];

    float* orow = out + (size_t)b * 1152;
#pragma unroll
    for (int o = 0; o < 9; o++) {
      const int ir = (o > 0) + (o > 3);
      float p0 = 0.f, p1 = 0.f;
#pragma unroll
      for (int k3 = 0; k3 < 6; k3++) {
        const int n = 6 * o + k3;
        const int nl = n & 31, ct = n >> 5;
        const int reg = (nl & 3) + 4 * (nl >> 3);
        const float cf = wv[ir * 10 + k3];
        if (((nl >> 2) & 1) == 0) p0 = fmaf(acc[ct][reg], cf, p0);
        else                      p1 = fmaf(acc[ct][reg], cf, p1);
      }
#pragma unroll
      for (int k2 = 0; k2 < 3; k2++) {
        const int n = 54 + 3 * o + k2;
        const int nl = n & 31, ct = n >> 5;
        const int reg = (nl & 3) + 4 * (nl >> 3);
        const float cf = wv[ir * 10 + 6 + k2];
        if (((nl >> 2) & 1) == 0) p0 = fmaf(acc[ct][reg], cf, p0);
        else                      p1 = fmaf(acc[ct][reg], cf, p1);
      }
      {
        const int n = 81 + o;
        const int nl = n & 31, ct = n >> 5;
        const int reg = (nl & 3) + 4 * (nl >> 3);
        const float cf = wv[ir * 10 + 9];
        if (((nl >> 2) & 1) == 0) p0 = fmaf(acc[ct][reg], cf, p0);
        else                      p1 = fmaf(acc[ct][reg], cf, p1);
      }
      float p = g2 ? p1 : p0;
      p += __shfl_xor(p, 32);
      const int col = (o == 0) ? c : (o < 4 ? 128 + 3 * c + (o - 1) : 512 + 5 * c + (o - 4));
      const bool mine = (o < 5) ? (g2 == 0) : (g2 == 1);
      if (mine) orow[col] = p;
    }
  }
}

extern "C" void kernel_launch(void* const* d_in, const int* in_sizes, int n_in,
                              void* d_out, int out_size, void* d_ws, size_t ws_size,
                              hipStream_t stream) {
  const float* x   = (const float*)d_in[0];
  const int*   idx = (const int*)d_in[1];
  const float* w   = (const float*)d_in[2];
  const float* U30 = (const float*)d_in[3];
  const float* U20 = (const float*)d_in[4];
  const float* U10 = (const float*)d_in[5];
  const float* U31 = (const float*)d_in[6];
  const float* U21 = (const float*)d_in[7];
  const float* U11 = (const float*)d_in[8];
  const float* U32 = (const float*)d_in[9];
  const float* U22 = (const float*)d_in[10];
  const float* U12 = (const float*)d_in[11];
  unsigned short* wsB = (unsigned short*)d_ws;
  float* out = (float*)d_out;

  prep_kernel<<<(UCHUNKS * 8 + 255) / 256, 256, 0, stream>>>(U30, U20, U10, U31, U21, U11, U32, U22, U12, wsB);
  symcon_mfma<<<NBLK, 256, 0, stream>>>(x, idx, w, wsB, out);
}

// Round 12
// 87.394 us; speedup vs baseline: 7.6315x; 1.1929x over previous
//
#include <hip/hip_runtime.h>

#define BATCH 2048
#define NTRI 165
#define NPAIR 45
#define NSTEP 14
#define UCHUNKS (NSTEP * 3 * 64)   // 2688 16B chunks = 43008 B

typedef __attribute__((ext_vector_type(8))) short s16x8;
typedef __attribute__((ext_vector_type(16))) float f32x16;
typedef __attribute__((ext_vector_type(4))) int i32x4;

// ---- compile-time tables ----
struct TriTab { unsigned char a[NTRI], b[NTRI], c[NTRI]; };
constexpr TriTab make_tri() {
  TriTab t{}; int q = 0;
  for (int a = 0; a < 9; a++) for (int b = a; b < 9; b++) for (int c = b; c < 9; c++) {
    t.a[q] = (unsigned char)a; t.b[q] = (unsigned char)b; t.c[q] = (unsigned char)c; q++;
  }
  return t;
}
constexpr TriTab TRI = make_tri();

struct PairTab { unsigned char a[NPAIR], b[NPAIR]; };
constexpr PairTab make_pair() {
  PairTab t{}; int q = 0;
  for (int a = 0; a < 9; a++) for (int b = a; b < 9; b++) {
    t.a[q] = (unsigned char)a; t.b[q] = (unsigned char)b; q++;
  }
  return t;
}
constexpr PairTab PAIR = make_pair();

// ---- prep: build bf16 U^T table in A-fragment-major order (direct table lookup) ----
// chunk (s,ct,lane) at byte ((s*3+ct)*64+lane)*16 holds 8 bf16:
//   n = ct*32 + (lane&31), k = s*16 + (lane>>5)*8 + j
__global__ void prep_kernel(const float* __restrict__ U30, const float* __restrict__ U20, const float* __restrict__ U10,
                            const float* __restrict__ U31, const float* __restrict__ U21, const float* __restrict__ U11,
                            const float* __restrict__ U32, const float* __restrict__ U22, const float* __restrict__ U12,
                            unsigned short* __restrict__ wsB) {
  int t = blockIdx.x * blockDim.x + threadIdx.x;
  if (t >= UCHUNKS * 8) return;
  int j = t & 7;
  int lane = (t >> 3) & 63;
  int cf = t >> 9;                 // s*3+ct, 0..41
  int s = cf / 3, ct = cf % 3;
  int n = ct * 32 + (lane & 31);
  int k = s * 16 + (lane >> 5) * 8 + j;
  const float* U3[3] = {U30, U31, U32};
  const float* U2[3] = {U20, U21, U22};
  const float* U1[3] = {U10, U11, U12};
  float val = 0.f;
  if (n < 54) {
    if (k < NTRI) {
      int o = n / 6, j3 = n % 6;
      int ir = (o > 0) + (o > 3); int lo = o - (ir == 1 ? 1 : (ir == 2 ? 4 : 0));
      int a = TRI.a[k], b = TRI.b[k], cc = TRI.c[k];
      int pm[6][3] = {{a,b,cc},{a,cc,b},{b,a,cc},{b,cc,a},{cc,a,b},{cc,b,a}};
      for (int p = 0; p < 6; p++) {
        bool dup = false;
        for (int rr = 0; rr < p; rr++)
          if (pm[rr][0] == pm[p][0] && pm[rr][1] == pm[p][1] && pm[rr][2] == pm[p][2]) dup = true;
        if (!dup) val += U3[ir][(((lo * 9 + pm[p][0]) * 9 + pm[p][1]) * 9 + pm[p][2]) * 6 + j3];
      }
    }
  } else if (n < 81) {
    if (k >= NTRI && k < NTRI + NPAIR) {
      int o = (n - 54) / 3, j2 = (n - 54) % 3;
      int ir = (o > 0) + (o > 3); int lo = o - (ir == 1 ? 1 : (ir == 2 ? 4 : 0));
      int p = k - NTRI;
      int a = PAIR.a[p], b = PAIR.b[p];
      val = U2[ir][((lo * 9 + a) * 9 + b) * 3 + j2];
      if (a != b) val += U2[ir][((lo * 9 + b) * 9 + a) * 3 + j2];
    }
  } else if (n < 90) {
    if (k >= 210 && k < 219) {
      int o = n - 81;
      int ir = (o > 0) + (o > 3); int lo = o - (ir == 1 ? 1 : (ir == 2 ? 4 : 0));
      val = U1[ir][lo * 9 + (k - 210)];
    }
  }
  unsigned u = __float_as_uint(val);
  unsigned r = (u + 0x7FFFu + ((u >> 16) & 1u)) >> 16;   // RNE to bf16
  wsB[t] = (unsigned short)r;
}

// ---- main: 2048 blocks x 256 threads, ZERO LDS ----
// U-fragments read directly from global wsB (43KB, L2/L3-resident, identical
// across all 2048 blocks). No staging, no barriers; occupancy limited only by
// VGPRs (~8 blocks/CU co-resident vs R6's 2). Theory: the invariant ~91us floor
// across six kernels was ordinary memory/dep latency with only 2 waves/SIMD to
// hide it; this maximizes TLP instead of fighting the dependency structure.
__global__ __launch_bounds__(256) void symcon_mfma(
    const float* __restrict__ x, const int* __restrict__ indices,
    const float* __restrict__ w, const unsigned short* __restrict__ wsB,
    float* __restrict__ out)
{
  const int tid = threadIdx.x;
  const int wave = tid >> 6;
  const int l = tid & 63;
  const int l5 = l & 31;
  const int g2 = l >> 5;

  const int b = blockIdx.x;
  const int c = wave * 32 + l5;                  // 0..127

  const float* xp = x + ((size_t)b * 128 + c) * 9;
  float xx[9];
#pragma unroll
  for (int i = 0; i < 9; i++) xx[i] = xp[i];

  // weight gather issued early so it overlaps the whole MFMA loop
  const int e = indices[b];
  const float* wbase = w + (size_t)e * 30 * 128 + c;
  float wv[30];
#pragma unroll
  for (int p = 0; p < 30; p++) wv[p] = wbase[p * 128];

  f32x16 acc[3];
#pragma unroll
  for (int ct = 0; ct < 3; ct++)
#pragma unroll
    for (int i = 0; i < 16; i++) acc[ct][i] = 0.f;

  const i32x4* Uf = (const i32x4*)wsB;

#pragma unroll
  for (int s = 0; s < NSTEP; s++) {
    float m[16];
#pragma unroll
    for (int t = 0; t < 16; t++) {
      const int k = s * 16 + t;
      if (k < NTRI)              m[t] = xx[TRI.a[k]] * xx[TRI.b[k]] * xx[TRI.c[k]];
      else if (k < NTRI + NPAIR) m[t] = xx[PAIR.a[k - NTRI]] * xx[PAIR.b[k - NTRI]];
      else if (k < 219)          m[t] = xx[k - 210];
      else                       m[t] = 0.f;
    }
    unsigned pk[4];
#pragma unroll
    for (int u = 0; u < 4; u++) {
      float lo = g2 ? m[8 + 2 * u]     : m[2 * u];
      float hi = g2 ? m[8 + 2 * u + 1] : m[2 * u + 1];
      asm("v_cvt_pk_bf16_f32 %0, %1, %2" : "=v"(pk[u]) : "v"(lo), "v"(hi));
    }
    i32x4 bi;
    bi[0] = (int)pk[0]; bi[1] = (int)pk[1]; bi[2] = (int)pk[2]; bi[3] = (int)pk[3];
    s16x8 bf = __builtin_bit_cast(s16x8, bi);
#pragma unroll
    for (int ct = 0; ct < 3; ct++) {
      // global read, 16B/lane coalesced; L2-hot (same 43KB for every block)
      i32x4 ua = Uf[(s * 3 + ct) * 64 + l];
      s16x8 af = __builtin_bit_cast(s16x8, ua);
      acc[ct] = __builtin_amdgcn_mfma_f32_32x32x16_bf16(af, bf, acc[ct], 0, 0, 0);
    }
  }

  // ---- in-register epilogue (R5-validated mapping) ----
  // acc[ct][reg] = D[n = ct*32 + (reg&3) + 8*(reg>>2) + 4*g2][batch = c]
  float* orow = out + (size_t)b * 1152;
#pragma unroll
  for (int o = 0; o < 9; o++) {
    const int ir = (o > 0) + (o > 3);
    float p0 = 0.f, p1 = 0.f;
#pragma unroll
    for (int k3 = 0; k3 < 6; k3++) {
      const int n = 6 * o + k3;
      const int nl = n & 31, ct = n >> 5;
      const int reg = (nl & 3) + 4 * (nl >> 3);
      const float cf = wv[ir * 10 + k3];
      if (((nl >> 2) & 1) == 0) p0 = fmaf(acc[ct][reg], cf, p0);
      else                      p1 = fmaf(acc[ct][reg], cf, p1);
    }
#pragma unroll
    for (int k2 = 0; k2 < 3; k2++) {
      const int n = 54 + 3 * o + k2;
      const int nl = n & 31, ct = n >> 5;
      const int reg = (nl & 3) + 4 * (nl >> 3);
      const float cf = wv[ir * 10 + 6 + k2];
      if (((nl >> 2) & 1) == 0) p0 = fmaf(acc[ct][reg], cf, p0);
      else                      p1 = fmaf(acc[ct][reg], cf, p1);
    }
    {
      const int n = 81 + o;
      const int nl = n & 31, ct = n >> 5;
      const int reg = (nl & 3) + 4 * (nl >> 3);
      const float cf = wv[ir * 10 + 9];
      if (((nl >> 2) & 1) == 0) p0 = fmaf(acc[ct][reg], cf, p0);
      else                      p1 = fmaf(acc[ct][reg], cf, p1);
    }
    float p = g2 ? p1 : p0;
    p += __shfl_xor(p, 32);
    const int col = (o == 0) ? c : (o < 4 ? 128 + 3 * c + (o - 1) : 512 + 5 * c + (o - 4));
    const bool mine = (o < 5) ? (g2 == 0) : (g2 == 1);
    if (mine) orow[col] = p;
  }
}

extern "C" void kernel_launch(void* const* d_in, const int* in_sizes, int n_in,
                              void* d_out, int out_size, void* d_ws, size_t ws_size,
                              hipStream_t stream) {
  const float* x   = (const float*)d_in[0];
  const int*   idx = (const int*)d_in[1];
  const float* w   = (const float*)d_in[2];
  const float* U30 = (const float*)d_in[3];
  const float* U20 = (const float*)d_in[4];
  const float* U10 = (const float*)d_in[5];
  const float* U31 = (const float*)d_in[6];
  const float* U21 = (const float*)d_in[7];
  const float* U11 = (const float*)d_in[8];
  const float* U32 = (const float*)d_in[9];
  const float* U22 = (const float*)d_in[10];
  const float* U12 = (const float*)d_in[11];
  unsigned short* wsB = (unsigned short*)d_ws;
  float* out = (float*)d_out;

  prep_kernel<<<(UCHUNKS * 8 + 255) / 256, 256, 0, stream>>>(U30, U20, U10, U31, U21, U11, U32, U22, U12, wsB);
  symcon_mfma<<<BATCH, 256, 0, stream>>>(x, idx, w, wsB, out);
}

// Round 13
// 42.101 us; speedup vs baseline: 15.8416x; 2.0758x over previous
//
#include <hip/hip_runtime.h>

#define BATCH 2048
#define NTRI 165
#define NPAIR 45
#define NSTEP 14
#define UCHUNKS (NSTEP * 3 * 64)   // 2688 16B chunks = 43008 B

typedef __attribute__((ext_vector_type(8))) short s16x8;
typedef __attribute__((ext_vector_type(16))) float f32x16;
typedef __attribute__((ext_vector_type(4))) int i32x4;

// ---- compile-time tables ----
struct TriTab { unsigned char a[NTRI], b[NTRI], c[NTRI]; };
constexpr TriTab make_tri() {
  TriTab t{}; int q = 0;
  for (int a = 0; a < 9; a++) for (int b = a; b < 9; b++) for (int c = b; c < 9; c++) {
    t.a[q] = (unsigned char)a; t.b[q] = (unsigned char)b; t.c[q] = (unsigned char)c; q++;
  }
  return t;
}
constexpr TriTab TRI = make_tri();

struct PairTab { unsigned char a[NPAIR], b[NPAIR]; };
constexpr PairTab make_pair() {
  PairTab t{}; int q = 0;
  for (int a = 0; a < 9; a++) for (int b = a; b < 9; b++) {
    t.a[q] = (unsigned char)a; t.b[q] = (unsigned char)b; q++;
  }
  return t;
}
constexpr PairTab PAIR = make_pair();

// ---- prep: build bf16 U^T table in A-fragment-major order ----
__global__ void prep_kernel(const float* __restrict__ U30, const float* __restrict__ U20, const float* __restrict__ U10,
                            const float* __restrict__ U31, const float* __restrict__ U21, const float* __restrict__ U11,
                            const float* __restrict__ U32, const float* __restrict__ U22, const float* __restrict__ U12,
                            unsigned short* __restrict__ wsB) {
  int t = blockIdx.x * blockDim.x + threadIdx.x;
  if (t >= UCHUNKS * 8) return;
  int j = t & 7;
  int lane = (t >> 3) & 63;
  int cf = t >> 9;                 // s*3+ct, 0..41
  int s = cf / 3, ct = cf % 3;
  int n = ct * 32 + (lane & 31);
  int k = s * 16 + (lane >> 5) * 8 + j;
  const float* U3[3] = {U30, U31, U32};
  const float* U2[3] = {U20, U21, U22};
  const float* U1[3] = {U10, U11, U12};
  float val = 0.f;
  if (n < 54) {
    if (k < NTRI) {
      int o = n / 6, j3 = n % 6;
      int ir = (o > 0) + (o > 3); int lo = o - (ir == 1 ? 1 : (ir == 2 ? 4 : 0));
      int a = TRI.a[k], b = TRI.b[k], cc = TRI.c[k];
      int pm[6][3] = {{a,b,cc},{a,cc,b},{b,a,cc},{b,cc,a},{cc,a,b},{cc,b,a}};
      for (int p = 0; p < 6; p++) {
        bool dup = false;
        for (int rr = 0; rr < p; rr++)
          if (pm[rr][0] == pm[p][0] && pm[rr][1] == pm[p][1] && pm[rr][2] == pm[p][2]) dup = true;
        if (!dup) val += U3[ir][(((lo * 9 + pm[p][0]) * 9 + pm[p][1]) * 9 + pm[p][2]) * 6 + j3];
      }
    }
  } else if (n < 81) {
    if (k >= NTRI && k < NTRI + NPAIR) {
      int o = (n - 54) / 3, j2 = (n - 54) % 3;
      int ir = (o > 0) + (o > 3); int lo = o - (ir == 1 ? 1 : (ir == 2 ? 4 : 0));
      int p = k - NTRI;
      int a = PAIR.a[p], b = PAIR.b[p];
      val = U2[ir][((lo * 9 + a) * 9 + b) * 3 + j2];
      if (a != b) val += U2[ir][((lo * 9 + b) * 9 + a) * 3 + j2];
    }
  } else if (n < 90) {
    if (k >= 210 && k < 219) {
      int o = n - 81;
      int ir = (o > 0) + (o > 3); int lo = o - (ir == 1 ? 1 : (ir == 2 ? 4 : 0));
      val = U1[ir][lo * 9 + (k - 210)];
    }
  }
  unsigned u = __float_as_uint(val);
  unsigned r = (u + 0x7FFFu + ((u >> 16) & 1u)) >> 16;   // RNE to bf16
  wsB[t] = (unsigned short)r;
}

// ---- compile-time monomial: no arrays, no alloca, nothing to demote to LDS ----
template<int K>
__device__ __forceinline__ float mono(const float* xx) {
  if constexpr (K < NTRI)              return xx[TRI.a[K]] * xx[TRI.b[K]] * xx[TRI.c[K]];
  else if constexpr (K < NTRI + NPAIR) return xx[PAIR.a[K - NTRI]] * xx[PAIR.b[K - NTRI]];
  else if constexpr (K < 219)          return xx[K - 210];
  else                                 return 0.f;
}

template<int S>
__device__ __forceinline__ void kstep(const float* xx, const int g2, const i32x4* Uf, const int l,
                                      f32x16& acc0, f32x16& acc1, f32x16& acc2) {
  unsigned q0, q1, q2, q3;
  {
    float lo = g2 ? mono<S*16+8>(xx)  : mono<S*16+0>(xx);
    float hi = g2 ? mono<S*16+9>(xx)  : mono<S*16+1>(xx);
    asm("v_cvt_pk_bf16_f32 %0, %1, %2" : "=v"(q0) : "v"(lo), "v"(hi));
  }
  {
    float lo = g2 ? mono<S*16+10>(xx) : mono<S*16+2>(xx);
    float hi = g2 ? mono<S*16+11>(xx) : mono<S*16+3>(xx);
    asm("v_cvt_pk_bf16_f32 %0, %1, %2" : "=v"(q1) : "v"(lo), "v"(hi));
  }
  {
    float lo = g2 ? mono<S*16+12>(xx) : mono<S*16+4>(xx);
    float hi = g2 ? mono<S*16+13>(xx) : mono<S*16+5>(xx);
    asm("v_cvt_pk_bf16_f32 %0, %1, %2" : "=v"(q2) : "v"(lo), "v"(hi));
  }
  {
    float lo = g2 ? mono<S*16+14>(xx) : mono<S*16+6>(xx);
    float hi = g2 ? mono<S*16+15>(xx) : mono<S*16+7>(xx);
    asm("v_cvt_pk_bf16_f32 %0, %1, %2" : "=v"(q3) : "v"(lo), "v"(hi));
  }
  i32x4 bi;
  bi[0] = (int)q0; bi[1] = (int)q1; bi[2] = (int)q2; bi[3] = (int)q3;
  s16x8 bf = __builtin_bit_cast(s16x8, bi);
  {
    i32x4 ua = Uf[(S * 3 + 0) * 64 + l];
    acc0 = __builtin_amdgcn_mfma_f32_32x32x16_bf16(__builtin_bit_cast(s16x8, ua), bf, acc0, 0, 0, 0);
  }
  {
    i32x4 ua = Uf[(S * 3 + 1) * 64 + l];
    acc1 = __builtin_amdgcn_mfma_f32_32x32x16_bf16(__builtin_bit_cast(s16x8, ua), bf, acc1, 0, 0, 0);
  }
  {
    i32x4 ua = Uf[(S * 3 + 2) * 64 + l];
    acc2 = __builtin_amdgcn_mfma_f32_32x32x16_bf16(__builtin_bit_cast(s16x8, ua), bf, acc2, 0, 0, 0);
  }
}

template<int S>
__device__ __forceinline__ void ksteps(const float* xx, const int g2, const i32x4* Uf, const int l,
                                       f32x16& acc0, f32x16& acc1, f32x16& acc2) {
  if constexpr (S < NSTEP) {
    kstep<S>(xx, g2, Uf, l, acc0, acc1, acc2);
    ksteps<S + 1>(xx, g2, Uf, l, acc0, acc1, acc2);
  }
}

#define ACCV(ct) ((ct) == 0 ? acc0 : (ct) == 1 ? acc1 : acc2)

// ---- main: 2048 blocks x 256 threads, zero LDS, no demotable allocas ----
__global__ __launch_bounds__(256) void symcon_mfma(
    const float* __restrict__ x, const int* __restrict__ indices,
    const float* __restrict__ w, const unsigned short* __restrict__ wsB,
    float* __restrict__ out)
{
  const int tid = threadIdx.x;
  const int wave = tid >> 6;
  const int l = tid & 63;
  const int l5 = l & 31;
  const int g2 = l >> 5;

  const int b = blockIdx.x;
  const int c = wave * 32 + l5;                  // 0..127

  const float* xp = x + ((size_t)b * 128 + c) * 9;
  float xx[9];
#pragma unroll
  for (int i = 0; i < 9; i++) xx[i] = xp[i];

  // weight gather issued early so it overlaps the whole MFMA loop
  const int e = indices[b];
  const float* wbase = w + (size_t)e * 30 * 128 + c;
  float wv[30];
#pragma unroll
  for (int p = 0; p < 30; p++) wv[p] = wbase[p * 128];

  f32x16 acc0, acc1, acc2;
#pragma unroll
  for (int i = 0; i < 16; i++) { acc0[i] = 0.f; acc1[i] = 0.f; acc2[i] = 0.f; }

  const i32x4* Uf = (const i32x4*)wsB;
  ksteps<0>(xx, g2, Uf, l, acc0, acc1, acc2);

  // ---- in-register epilogue (R5-validated mapping) ----
  // ACCV(ct)[reg] = D[n = ct*32 + (reg&3) + 8*(reg>>2) + 4*g2][batch = c]
  float* orow = out + (size_t)b * 1152;
#pragma unroll
  for (int o = 0; o < 9; o++) {
    const int ir = (o > 0) + (o > 3);
    float p0 = 0.f, p1 = 0.f;
#pragma unroll
    for (int k3 = 0; k3 < 6; k3++) {
      const int n = 6 * o + k3;
      const int nl = n & 31, ct = n >> 5;
      const int reg = (nl & 3) + 4 * (nl >> 3);
      const float cf = wv[ir * 10 + k3];
      if (((nl >> 2) & 1) == 0) p0 = fmaf(ACCV(ct)[reg], cf, p0);
      else                      p1 = fmaf(ACCV(ct)[reg], cf, p1);
    }
#pragma unroll
    for (int k2 = 0; k2 < 3; k2++) {
      const int n = 54 + 3 * o + k2;
      const int nl = n & 31, ct = n >> 5;
      const int reg = (nl & 3) + 4 * (nl >> 3);
      const float cf = wv[ir * 10 + 6 + k2];
      if (((nl >> 2) & 1) == 0) p0 = fmaf(ACCV(ct)[reg], cf, p0);
      else                      p1 = fmaf(ACCV(ct)[reg], cf, p1);
    }
    {
      const int n = 81 + o;
      const int nl = n & 31, ct = n >> 5;
      const int reg = (nl & 3) + 4 * (nl >> 3);
      const float cf = wv[ir * 10 + 9];
      if (((nl >> 2) & 1) == 0) p0 = fmaf(ACCV(ct)[reg], cf, p0);
      else                      p1 = fmaf(ACCV(ct)[reg], cf, p1);
    }
    float p = g2 ? p1 : p0;
    p += __shfl_xor(p, 32);
    const int col = (o == 0) ? c : (o < 4 ? 128 + 3 * c + (o - 1) : 512 + 5 * c + (o - 4));
    const bool mine = (o < 5) ? (g2 == 0) : (g2 == 1);
    if (mine) orow[col] = p;
  }
}

extern "C" void kernel_launch(void* const* d_in, const int* in_sizes, int n_in,
                              void* d_out, int out_size, void* d_ws, size_t ws_size,
                              hipStream_t stream) {
  const float* x   = (const float*)d_in[0];
  const int*   idx = (const int*)d_in[1];
  const float* w   = (const float*)d_in[2];
  const float* U30 = (const float*)d_in[3];
  const float* U20 = (const float*)d_in[4];
  const float* U10 = (const float*)d_in[5];
  const float* U31 = (const float*)d_in[6];
  const float* U21 = (const float*)d_in[7];
  const float* U11 = (const float*)d_in[8];
  const float* U32 = (const float*)d_in[9];
  const float* U22 = (const float*)d_in[10];
  const float* U12 = (const float*)d_in[11];
  unsigned short* wsB = (unsigned short*)d_ws;
  float* out = (float*)d_out;

  prep_kernel<<<(UCHUNKS * 8 + 255) / 256, 256, 0, stream>>>(U30, U20, U10, U31, U21, U11, U32, U22, U12, wsB);
  symcon_mfma<<<BATCH, 256, 0, stream>>>(x, idx, w, wsB, out);
}

// Round 14
// 35.585 us; speedup vs baseline: 18.7425x; 1.1831x over previous
//
#include <hip/hip_runtime.h>

#define BATCH 2048
#define NTRI 165
#define NPAIR 45
#define NSTEP 14
#define UCHUNKS (NSTEP * 3 * 64)   // 2688 16B chunks = 43008 B

typedef __attribute__((ext_vector_type(8))) short s16x8;
typedef __attribute__((ext_vector_type(16))) float f32x16;
typedef __attribute__((ext_vector_type(4))) int i32x4;

// ---- compile-time tables ----
struct TriTab { unsigned char a[NTRI], b[NTRI], c[NTRI]; };
constexpr TriTab make_tri() {
  TriTab t{}; int q = 0;
  for (int a = 0; a < 9; a++) for (int b = a; b < 9; b++) for (int c = b; c < 9; c++) {
    t.a[q] = (unsigned char)a; t.b[q] = (unsigned char)b; t.c[q] = (unsigned char)c; q++;
  }
  return t;
}
constexpr TriTab TRI = make_tri();

struct PairTab { unsigned char a[NPAIR], b[NPAIR]; };
constexpr PairTab make_pair() {
  PairTab t{}; int q = 0;
  for (int a = 0; a < 9; a++) for (int b = a; b < 9; b++) {
    t.a[q] = (unsigned char)a; t.b[q] = (unsigned char)b; q++;
  }
  return t;
}
constexpr PairTab PAIR = make_pair();

// ---- prep: build bf16 U^T table in A-fragment-major order ----
__global__ void prep_kernel(const float* __restrict__ U30, const float* __restrict__ U20, const float* __restrict__ U10,
                            const float* __restrict__ U31, const float* __restrict__ U21, const float* __restrict__ U11,
                            const float* __restrict__ U32, const float* __restrict__ U22, const float* __restrict__ U12,
                            unsigned short* __restrict__ wsB) {
  int t = blockIdx.x * blockDim.x + threadIdx.x;
  if (t >= UCHUNKS * 8) return;
  int j = t & 7;
  int lane = (t >> 3) & 63;
  int cf = t >> 9;                 // s*3+ct, 0..41
  int s = cf / 3, ct = cf % 3;
  int n = ct * 32 + (lane & 31);
  int k = s * 16 + (lane >> 5) * 8 + j;
  const float* U3[3] = {U30, U31, U32};
  const float* U2[3] = {U20, U21, U22};
  const float* U1[3] = {U10, U11, U12};
  float val = 0.f;
  if (n < 54) {
    if (k < NTRI) {
      int o = n / 6, j3 = n % 6;
      int ir = (o > 0) + (o > 3); int lo = o - (ir == 1 ? 1 : (ir == 2 ? 4 : 0));
      int a = TRI.a[k], b = TRI.b[k], cc = TRI.c[k];
      int pm[6][3] = {{a,b,cc},{a,cc,b},{b,a,cc},{b,cc,a},{cc,a,b},{cc,b,a}};
      for (int p = 0; p < 6; p++) {
        bool dup = false;
        for (int rr = 0; rr < p; rr++)
          if (pm[rr][0] == pm[p][0] && pm[rr][1] == pm[p][1] && pm[rr][2] == pm[p][2]) dup = true;
        if (!dup) val += U3[ir][(((lo * 9 + pm[p][0]) * 9 + pm[p][1]) * 9 + pm[p][2]) * 6 + j3];
      }
    }
  } else if (n < 81) {
    if (k >= NTRI && k < NTRI + NPAIR) {
      int o = (n - 54) / 3, j2 = (n - 54) % 3;
      int ir = (o > 0) + (o > 3); int lo = o - (ir == 1 ? 1 : (ir == 2 ? 4 : 0));
      int p = k - NTRI;
      int a = PAIR.a[p], b = PAIR.b[p];
      val = U2[ir][((lo * 9 + a) * 9 + b) * 3 + j2];
      if (a != b) val += U2[ir][((lo * 9 + b) * 9 + a) * 3 + j2];
    }
  } else if (n < 90) {
    if (k >= 210 && k < 219) {
      int o = n - 81;
      int ir = (o > 0) + (o > 3); int lo = o - (ir == 1 ? 1 : (ir == 2 ? 4 : 0));
      val = U1[ir][lo * 9 + (k - 210)];
    }
  }
  unsigned u = __float_as_uint(val);
  unsigned r = (u + 0x7FFFu + ((u >> 16) & 1u)) >> 16;   // RNE to bf16
  wsB[t] = (unsigned short)r;
}

// ---- compile-time monomial: no arrays, no alloca, nothing to demote to LDS ----
template<int K>
__device__ __forceinline__ float mono(const float* xx) {
  if constexpr (K < NTRI)              return xx[TRI.a[K]] * xx[TRI.b[K]] * xx[TRI.c[K]];
  else if constexpr (K < NTRI + NPAIR) return xx[PAIR.a[K - NTRI]] * xx[PAIR.b[K - NTRI]];
  else if constexpr (K < 219)          return xx[K - 210];
  else                                 return 0.f;
}

// ---- 2-step software-pipelined k-chain: consume step S, prefetch step S+2 ----
template<int S>
__device__ __forceinline__ void pipe(const float* xx, const int g2, const i32x4* Uf, const int l,
                                     f32x16& acc0, f32x16& acc1, f32x16& acc2,
                                     i32x4 c0, i32x4 c1, i32x4 c2,      // chunks for step S
                                     i32x4 n0, i32x4 n1, i32x4 n2) {    // chunks for step S+1
  i32x4 f0{}, f1{}, f2{};
  if constexpr (S + 2 < NSTEP) {     // issue S+2 loads before the VALU/MFMA body
    f0 = Uf[((S + 2) * 3 + 0) * 64 + l];
    f1 = Uf[((S + 2) * 3 + 1) * 64 + l];
    f2 = Uf[((S + 2) * 3 + 2) * 64 + l];
  }
  unsigned q0, q1, q2, q3;
  {
    float lo = g2 ? mono<S*16+8>(xx)  : mono<S*16+0>(xx);
    float hi = g2 ? mono<S*16+9>(xx)  : mono<S*16+1>(xx);
    asm("v_cvt_pk_bf16_f32 %0, %1, %2" : "=v"(q0) : "v"(lo), "v"(hi));
  }
  {
    float lo = g2 ? mono<S*16+10>(xx) : mono<S*16+2>(xx);
    float hi = g2 ? mono<S*16+11>(xx) : mono<S*16+3>(xx);
    asm("v_cvt_pk_bf16_f32 %0, %1, %2" : "=v"(q1) : "v"(lo), "v"(hi));
  }
  {
    float lo = g2 ? mono<S*16+12>(xx) : mono<S*16+4>(xx);
    float hi = g2 ? mono<S*16+13>(xx) : mono<S*16+5>(xx);
    asm("v_cvt_pk_bf16_f32 %0, %1, %2" : "=v"(q2) : "v"(lo), "v"(hi));
  }
  {
    float lo = g2 ? mono<S*16+14>(xx) : mono<S*16+6>(xx);
    float hi = g2 ? mono<S*16+15>(xx) : mono<S*16+7>(xx);
    asm("v_cvt_pk_bf16_f32 %0, %1, %2" : "=v"(q3) : "v"(lo), "v"(hi));
  }
  i32x4 bi;
  bi[0] = (int)q0; bi[1] = (int)q1; bi[2] = (int)q2; bi[3] = (int)q3;
  s16x8 bf = __builtin_bit_cast(s16x8, bi);
  acc0 = __builtin_amdgcn_mfma_f32_32x32x16_bf16(__builtin_bit_cast(s16x8, c0), bf, acc0, 0, 0, 0);
  acc1 = __builtin_amdgcn_mfma_f32_32x32x16_bf16(__builtin_bit_cast(s16x8, c1), bf, acc1, 0, 0, 0);
  acc2 = __builtin_amdgcn_mfma_f32_32x32x16_bf16(__builtin_bit_cast(s16x8, c2), bf, acc2, 0, 0, 0);
  if constexpr (S + 1 < NSTEP)
    pipe<S + 1>(xx, g2, Uf, l, acc0, acc1, acc2, n0, n1, n2, f0, f1, f2);
}

#define ACCV(ct) ((ct) == 0 ? acc0 : (ct) == 1 ? acc1 : acc2)

// ---- main: 2048 blocks x 256 threads, zero LDS, pipelined U prefetch ----
__global__ __launch_bounds__(256) void symcon_mfma(
    const float* __restrict__ x, const int* __restrict__ indices,
    const float* __restrict__ w, const unsigned short* __restrict__ wsB,
    float* __restrict__ out)
{
  const int tid = threadIdx.x;
  const int wave = tid >> 6;
  const int l = tid & 63;
  const int l5 = l & 31;
  const int g2 = l >> 5;

  const int b = blockIdx.x;
  const int c = wave * 32 + l5;                  // 0..127

  const float* xp = x + ((size_t)b * 128 + c) * 9;
  float xx[9];
#pragma unroll
  for (int i = 0; i < 9; i++) xx[i] = xp[i];

  const int e = indices[b];                      // scalar, issued early

  f32x16 acc0, acc1, acc2;
#pragma unroll
  for (int i = 0; i < 16; i++) { acc0[i] = 0.f; acc1[i] = 0.f; acc2[i] = 0.f; }

  const i32x4* Uf = (const i32x4*)wsB;
  // prologue: preload steps 0 and 1
  i32x4 p0 = Uf[0 * 64 + l], p1 = Uf[1 * 64 + l], p2 = Uf[2 * 64 + l];
  i32x4 r0 = Uf[3 * 64 + l], r1 = Uf[4 * 64 + l], r2 = Uf[5 * 64 + l];
  pipe<0>(xx, g2, Uf, l, acc0, acc1, acc2, p0, p1, p2, r0, r1, r2);

  // ---- weight gather AFTER the loop: 30 VGPRs not held across the MFMA body ----
  const float* wbase = w + (size_t)e * 30 * 128 + c;
  float wv[30];
#pragma unroll
  for (int p = 0; p < 30; p++) wv[p] = wbase[p * 128];

  // ---- in-register epilogue (R5-validated mapping) ----
  // ACCV(ct)[reg] = D[n = ct*32 + (reg&3) + 8*(reg>>2) + 4*g2][batch = c]
  float* orow = out + (size_t)b * 1152;
#pragma unroll
  for (int o = 0; o < 9; o++) {
    const int ir = (o > 0) + (o > 3);
    float p0f = 0.f, p1f = 0.f;
#pragma unroll
    for (int k3 = 0; k3 < 6; k3++) {
      const int n = 6 * o + k3;
      const int nl = n & 31, ct = n >> 5;
      const int reg = (nl & 3) + 4 * (nl >> 3);
      const float cf = wv[ir * 10 + k3];
      if (((nl >> 2) & 1) == 0) p0f = fmaf(ACCV(ct)[reg], cf, p0f);
      else                      p1f = fmaf(ACCV(ct)[reg], cf, p1f);
    }
#pragma unroll
    for (int k2 = 0; k2 < 3; k2++) {
      const int n = 54 + 3 * o + k2;
      const int nl = n & 31, ct = n >> 5;
      const int reg = (nl & 3) + 4 * (nl >> 3);
      const float cf = wv[ir * 10 + 6 + k2];
      if (((nl >> 2) & 1) == 0) p0f = fmaf(ACCV(ct)[reg], cf, p0f);
      else                      p1f = fmaf(ACCV(ct)[reg], cf, p1f);
    }
    {
      const int n = 81 + o;
      const int nl = n & 31, ct = n >> 5;
      const int reg = (nl & 3) + 4 * (nl >> 3);
      const float cf = wv[ir * 10 + 9];
      if (((nl >> 2) & 1) == 0) p0f = fmaf(ACCV(ct)[reg], cf, p0f);
      else                      p1f = fmaf(ACCV(ct)[reg], cf, p1f);
    }
    float p = g2 ? p1f : p0f;
    p += __shfl_xor(p, 32);
    const int col = (o == 0) ? c : (o < 4 ? 128 + 3 * c + (o - 1) : 512 + 5 * c + (o - 4));
    const bool mine = (o < 5) ? (g2 == 0) : (g2 == 1);
    if (mine) orow[col] = p;
  }
}

extern "C" void kernel_launch(void* const* d_in, const int* in_sizes, int n_in,
                              void* d_out, int out_size, void* d_ws, size_t ws_size,
                              hipStream_t stream) {
  const float* x   = (const float*)d_in[0];
  const int*   idx = (const int*)d_in[1];
  const float* w   = (const float*)d_in[2];
  const float* U30 = (const float*)d_in[3];
  const float* U20 = (const float*)d_in[4];
  const float* U10 = (const float*)d_in[5];
  const float* U31 = (const float*)d_in[6];
  const float* U21 = (const float*)d_in[7];
  const float* U11 = (const float*)d_in[8];
  const float* U32 = (const float*)d_in[9];
  const float* U22 = (const float*)d_in[10];
  const float* U12 = (const float*)d_in[11];
  unsigned short* wsB = (unsigned short*)d_ws;
  float* out = (float*)d_out;

  prep_kernel<<<(UCHUNKS * 8 + 255) / 256, 256, 0, stream>>>(U30, U20, U10, U31, U21, U11, U32, U22, U12, wsB);
  symcon_mfma<<<BATCH, 256, 0, stream>>>(x, idx, w, wsB, out);
}